// Round 12
// baseline (125.827 us; speedup 1.0000x reference)
//
#include <hip/hip_runtime.h>
#include <math.h>

#define BB 4
#define TT 128
#define DD 768
#define HD 770
#define HP 800
#define LL 40
#define TP1 129

typedef __attribute__((ext_vector_type(8))) short s16x8;
typedef __attribute__((ext_vector_type(4))) float f32x4;

// ws float offsets
#define P_OFF   0
#define Q_OFF   409600          // 512*800
#define W2F_OFF 819200          // 4800 uint4 = 19200 u32
#define ACC_OFF 838400          // 160 floats

__device__ __forceinline__ unsigned pkbf(float a, float b) {
    unsigned ua = __float_as_uint(a);
    unsigned ub = __float_as_uint(b);
    return ((ua + 0x8000u) >> 16) | ((ub + 0x8000u) & 0xffff0000u);
}
__device__ __forceinline__ unsigned rne1(float v) {
    unsigned x = __float_as_uint(v);
    return (x + 0x7fffu + ((x >> 16) & 1u)) >> 16;
}
// intra-wave LDS ordering only — no s_barrier
__device__ __forceinline__ void ldswait() {
    asm volatile("s_waitcnt lgkmcnt(0)" ::: "memory");
}

// ====== kA (R10-proven): fused prep + X@{W1a,W1b} GEMM, B-frags in LDS ======
__global__ __launch_bounds__(256) void kA(const float* __restrict__ hidden,
                                          const float* __restrict__ W1,
                                          const float* __restrict__ W2,
                                          const float* __restrict__ b1,
                                          float* __restrict__ P,
                                          float* __restrict__ Q,
                                          unsigned* __restrict__ W2f,
                                          float* __restrict__ accum) {
    __shared__ uint4 Bl[3072];   // 48 KB: [half 0..1][ks 0..23][lane 0..63]
    const int bx  = blockIdx.x;
    const int tid = threadIdx.x;

    if (bx < 392) {
        const int nt = bx / 8;          // 0..48
        const int mg = bx - nt * 8;     // 0..7
        const int lane = tid & 63;
        const int col  = lane & 15;
        const int quad = lane >> 4;

        for (int u = tid; u < 3072; u += 256) {
            int half = u / 1536;
            int rem  = u - half * 1536;
            int ks = rem >> 6;
            int ln = rem & 63;
            int kbase = ks * 32 + ((ln >> 4) << 3);
            int h = nt * 16 + (ln & 15);
            int row0 = half * DD + kbase;
            unsigned pk[4];
            #pragma unroll
            for (int sp = 0; sp < 4; ++sp) {
                unsigned w[2];
                #pragma unroll
                for (int e = 0; e < 2; ++e) {
                    float v = (h < HD) ? W1[(size_t)(row0 + 2 * sp + e) * HD + h] : 0.0f;
                    w[e] = rne1(v);
                }
                pk[sp] = w[0] | (w[1] << 16);
            }
            Bl[u] = make_uint4(pk[0], pk[1], pk[2], pk[3]);
        }
        __syncthreads();

        const int mband = mg * 4 + (tid >> 6);   // 0..31
        const int b  = mband >> 3;
        const int tt = mband & 7;

        const float* __restrict__ Arow =
            hidden + (size_t)(b * TP1 + 1 + tt * 16 + col) * DD + (quad << 3);

        f32x4 a0 = (f32x4){0.f, 0.f, 0.f, 0.f};
        f32x4 a1 = (f32x4){0.f, 0.f, 0.f, 0.f};

        #pragma unroll 4
        for (int ks = 0; ks < 24; ++ks) {
            float4 x0 = *(const float4*)(Arow + ks * 32);
            float4 x1 = *(const float4*)(Arow + ks * 32 + 4);
            union { unsigned u[4]; s16x8 v; } af;
            af.u[0] = pkbf(x0.x, x0.y); af.u[1] = pkbf(x0.z, x0.w);
            af.u[2] = pkbf(x1.x, x1.y); af.u[3] = pkbf(x1.z, x1.w);
            union { uint4 q; s16x8 v; } bf0, bf1;
            bf0.q = Bl[ks * 64 + lane];
            bf1.q = Bl[1536 + ks * 64 + lane];
            a0 = __builtin_amdgcn_mfma_f32_16x16x32_bf16(af.v, bf0.v, a0, 0, 0, 0);
            a1 = __builtin_amdgcn_mfma_f32_16x16x32_bf16(af.v, bf1.v, a1, 0, 0, 0);
        }

        const int h = nt * 16 + col;
        if (h < HD) {
            const float bv = b1[h];
            #pragma unroll
            for (int r = 0; r < 4; ++r) {
                int t = tt * 16 + quad * 4 + r;
                size_t row = (size_t)(b * TT + t) * HP;
                P[row + h] = a0[r] + bv;
                Q[row + h] = a1[r];
            }
        }
    } else if (bx < 411) {
        int u = (bx - 392) * 256 + tid;
        if (u >= 4800) return;
        int nt = u / 1600;
        int rem = u - nt * 1600;
        int ks = rem >> 6;
        int ln = rem & 63;
        int kbase = ks * 32 + ((ln >> 4) << 3);
        int l = nt * 16 + (ln & 15);
        unsigned pk[4];
        #pragma unroll
        for (int sp = 0; sp < 4; ++sp) {
            unsigned w[2];
            #pragma unroll
            for (int e = 0; e < 2; ++e) {
                int k = kbase + 2 * sp + e;
                float v = (k < HD && l < LL) ? W2[k * LL + l] : 0.0f;
                w[e] = rne1(v);
            }
            pk[sp] = w[0] | (w[1] << 16);
        }
        ((uint4*)W2f)[u] = make_uint4(pk[0], pk[1], pk[2], pk[3]);
    } else if (bx == 411) {
        if (tid < 160) accum[tid] = 0.0f;
    } else {
        int u = (bx - 412) * 256 + tid;       // < 15360
        int row = u / 30;
        int h = HD + (u - row * 30);          // [770,800)
        Q[(size_t)row * HP + h] = 0.0f;
    }
}

// ====== kB: j-split (1024 blocks), barrier-free K-loop (wave-closed Sb) ======
// block=(jh,i,b), 4 waves; wave = 16-row j-tile x 3 l-tiles; K=800/32=25 chunks.
__global__ __launch_bounds__(256) void kB(const float* __restrict__ P,
                                          const float* __restrict__ Q,
                                          const float* __restrict__ W1,
                                          const unsigned* __restrict__ W2f,
                                          const float* __restrict__ b2,
                                          const int* __restrict__ spans,
                                          const int* __restrict__ avail,
                                          float* __restrict__ out,
                                          float* __restrict__ accum) {
    __shared__ unsigned Sb[2][64 * 20];   // 10 KB, row=32h=16dw +4 pad
    __shared__ float var[3 * HP];         // 9.6 KB
    __shared__ int avi[64];
    __shared__ float sred[192];

    const int jh = blockIdx.x;            // 0..1
    const int i  = blockIdx.y;
    const int b  = blockIdx.z;
    const int tid = threadIdx.x;
    const int wave = tid >> 6;
    const int lane = tid & 63;
    const int col  = lane & 15;
    const int quad = lane >> 4;

    const int start = spans[b * 2];
    const int end   = spans[b * 2 + 1];

    // stage var (3 ind-variants) + avail slice
    {
        const float* Pi  = P + (size_t)(b * TT + i) * HP;
        const float* w1L = W1 + (size_t)2 * DD * HD;
        for (int h = tid; h < HP; h += 256) {
            float pv = (h < HD) ? Pi[h] : 0.0f;
            float wv = (h < HD) ? w1L[h] : 0.0f;
            var[h]        = pv;
            var[HP + h]   = pv + wv;
            var[2*HP + h] = pv + wv + wv;
        }
        if (tid < 64) avi[tid] = avail[i * TT + jh * 64 + tid];
    }
    __syncthreads();   // var/avi visible to all; ONLY barrier before epilogue

    // producer role: thread covers row jloc = tid>>2, h-offset hh = (tid&3)*8
    const int jloc = tid >> 2;
    const int jS   = jh * 64 + jloc;
    const int hh   = (tid & 3) << 3;
    int indS;
    {
        bool f = (i == start) && (jS == end);
        indS = f ? 2 : (((start <= i) && (i <= jS) && (jS <= end)) ? 1 : 0);
    }
    const float* __restrict__ Qj = Q + (size_t)(b * TT + jS) * HP;
    const float* vb = var + indS * HP;
    const int sdst = jloc * 20 + ((tid & 3) << 2);

    auto pack8 = [&](int c, int p, float4 qa, float4 qb) {
        const int h0 = c * 32 + hh;
        float4 v0 = *(const float4*)(vb + h0);
        float4 v1 = *(const float4*)(vb + h0 + 4);
        float s0 = fmaxf(v0.x + qa.x, 0.f), s1 = fmaxf(v0.y + qa.y, 0.f);
        float s2 = fmaxf(v0.z + qa.z, 0.f), s3 = fmaxf(v0.w + qa.w, 0.f);
        float s4 = fmaxf(v1.x + qb.x, 0.f), s5 = fmaxf(v1.y + qb.y, 0.f);
        float s6 = fmaxf(v1.z + qb.z, 0.f), s7 = fmaxf(v1.w + qb.w, 0.f);
        *(uint4*)(&Sb[p][sdst]) =
            make_uint4(pkbf(s0,s1), pkbf(s2,s3), pkbf(s4,s5), pkbf(s6,s7));
    };

    f32x4 acc[3];
    #pragma unroll
    for (int nt = 0; nt < 3; ++nt) acc[nt] = (f32x4){0.f, 0.f, 0.f, 0.f};

    // prologue: pack chunk 0; prefetch chunk 1 into registers
    float4 ca, cb;
    {
        const float4* qp = (const float4*)(Qj + hh);
        pack8(0, 0, qp[0], qp[1]);
        const float4* qn = (const float4*)(Qj + 32 + hh);
        ca = qn[0]; cb = qn[1];
    }
    ldswait();   // ds_writes complete before this wave's ds_reads

    // consumer: wave's A-frag rows jloc [wave*16, wave*16+16)
    const int arow0 = (wave * 16 + col) * 20 + (quad << 2);
    #pragma unroll
    for (int c = 0; c < 25; ++c) {
        const int p = c & 1;
        s16x8 bf0 = *(const s16x8*)((const unsigned*)W2f + (( 0 + c) * 64 + lane) * 4);
        s16x8 bf1 = *(const s16x8*)((const unsigned*)W2f + ((25 + c) * 64 + lane) * 4);
        s16x8 bf2 = *(const s16x8*)((const unsigned*)W2f + ((50 + c) * 64 + lane) * 4);
        s16x8 af  = *(const s16x8*)(&Sb[p][arow0]);
        if (c + 1 < 25) {
            float4 fa = ca, fb = cb;
            if (c + 2 < 25) {   // issue loads for c+2 (independent of fa/fb)
                const float4* qn = (const float4*)(Qj + (c + 2) * 32 + hh);
                ca = qn[0]; cb = qn[1];
            }
            pack8(c + 1, p ^ 1, fa, fb);
        }
        acc[0] = __builtin_amdgcn_mfma_f32_16x16x32_bf16(af, bf0, acc[0], 0, 0, 0);
        acc[1] = __builtin_amdgcn_mfma_f32_16x16x32_bf16(af, bf1, acc[1], 0, 0, 0);
        acc[2] = __builtin_amdgcn_mfma_f32_16x16x32_bf16(af, bf2, acc[2], 0, 0, 0);
        ldswait();   // intra-wave write->read ordering; no s_barrier
    }

    // epilogue: write out + fused exp-sum
    float bias[3];
    #pragma unroll
    for (int nt = 0; nt < 3; ++nt) {
        int l = nt * 16 + col;
        bias[nt] = (l < LL) ? b2[l] : 0.0f;
    }
    float sE[3] = {0.f, 0.f, 0.f};
    #pragma unroll
    for (int r = 0; r < 4; ++r) {
        int aj = wave * 16 + quad * 4 + r;       // local j
        int j  = jh * 64 + aj;
        bool msk = avi[aj] >= 1;
        size_t rowoff = ((size_t)(b * (TT * TT) + i * TT + j)) * LL;
        #pragma unroll
        for (int nt = 0; nt < 3; ++nt) {
            int l = nt * 16 + col;
            if (l < LL) {
                float val = msk ? (acc[nt][r] + bias[nt]) : 0.0f;
                out[rowoff + l] = val;
                sE[nt] += __expf(val);
            }
        }
    }
    #pragma unroll
    for (int nt = 0; nt < 3; ++nt) {
        float v = sE[nt];
        v += __shfl_xor(v, 16);
        v += __shfl_xor(v, 32);
        if (lane < 16) sred[wave * 48 + nt * 16 + lane] = v;
    }
    __syncthreads();
    if (tid < 48) {
        float t4 = sred[tid] + sred[48 + tid] + sred[96 + tid] + sred[144 + tid];
        if (tid < LL) atomicAdd(&accum[b * LL + tid], t4);
    }
}

// ================= kD: out -= log(denom) =================
__global__ __launch_bounds__(256) void kD(float* __restrict__ out,
                                          const float* __restrict__ accum) {
    const int idx = blockIdx.x * 256 + threadIdx.x;
    const int e = idx * 4;
    const int b = e / (TT * TT * LL);
    const int l = e % LL;
    float4 v = ((float4*)out)[idx];
    const float* ac = accum + b * LL + l;
    v.x -= __logf(ac[0]); v.y -= __logf(ac[1]);
    v.z -= __logf(ac[2]); v.w -= __logf(ac[3]);
    ((float4*)out)[idx] = v;
}

extern "C" void kernel_launch(void* const* d_in, const int* in_sizes, int n_in,
                              void* d_out, int out_size, void* d_ws, size_t ws_size,
                              hipStream_t stream) {
    const float* hidden = (const float*)d_in[0];
    const float* W1     = (const float*)d_in[1];
    const float* b1     = (const float*)d_in[2];
    const float* W2     = (const float*)d_in[3];
    const float* b2     = (const float*)d_in[4];
    const int*   spans  = (const int*)d_in[5];
    const int*   avail  = (const int*)d_in[6];
    float* out = (float*)d_out;
    float* ws  = (float*)d_ws;

    float*    P     = ws + P_OFF;
    float*    Q     = ws + Q_OFF;
    unsigned* W2f   = (unsigned*)(ws + W2F_OFF);
    float*    accum = ws + ACC_OFF;

    kA <<<dim3(472),        dim3(256), 0, stream>>>(hidden, W1, W2, b1, P, Q, W2f, accum);
    kB <<<dim3(2, TT, BB),  dim3(256), 0, stream>>>(P, Q, W1, W2f, b2, spans, avail, out, accum);
    kD <<<dim3(2560),       dim3(256), 0, stream>>>(out, accum);
}

// Round 13
// 123.756 us; speedup vs baseline: 1.0167x; 1.0167x over previous
//
#include <hip/hip_runtime.h>
#include <math.h>

#define BB 4
#define TT 128
#define DD 768
#define HD 770
#define HP 800
#define LL 40
#define TP1 129

typedef __attribute__((ext_vector_type(8))) short s16x8;
typedef __attribute__((ext_vector_type(4))) float f32x4;

// ws float offsets
#define P_OFF   0
#define Q_OFF   409600          // 512*800
#define W2F_OFF 819200          // 4800 uint4 = 19200 u32
#define ACC_OFF 838400          // 160 floats

__device__ __forceinline__ unsigned pkbf(float a, float b) {
    unsigned ua = __float_as_uint(a);
    unsigned ub = __float_as_uint(b);
    return ((ua + 0x8000u) >> 16) | ((ub + 0x8000u) & 0xffff0000u);
}
__device__ __forceinline__ unsigned rne1(float v) {
    unsigned x = __float_as_uint(v);
    return (x + 0x7fffu + ((x >> 16) & 1u)) >> 16;
}
// lgkm-only barrier: ds ops drained, global loads stay in flight
__device__ __forceinline__ void ldsbar() {
    asm volatile("s_waitcnt lgkmcnt(0)\n\ts_barrier" ::: "memory");
}

// ====== kA: fused prep + X@{W1a,W1b} GEMM, B-frags in LDS; A-loads pipelined ======
__global__ __launch_bounds__(256) void kA(const float* __restrict__ hidden,
                                          const float* __restrict__ W1,
                                          const float* __restrict__ W2,
                                          const float* __restrict__ b1,
                                          float* __restrict__ P,
                                          float* __restrict__ Q,
                                          unsigned* __restrict__ W2f,
                                          float* __restrict__ accum) {
    __shared__ uint4 Bl[3072];   // 48 KB: [half 0..1][ks 0..23][lane 0..63]
    const int bx  = blockIdx.x;
    const int tid = threadIdx.x;

    if (bx < 392) {
        const int nt = bx / 8;          // 0..48
        const int mg = bx - nt * 8;     // 0..7
        const int lane = tid & 63;
        const int col  = lane & 15;
        const int quad = lane >> 4;

        for (int u = tid; u < 3072; u += 256) {
            int half = u / 1536;
            int rem  = u - half * 1536;
            int ks = rem >> 6;
            int ln = rem & 63;
            int kbase = ks * 32 + ((ln >> 4) << 3);
            int h = nt * 16 + (ln & 15);
            int row0 = half * DD + kbase;
            unsigned pk[4];
            #pragma unroll
            for (int sp = 0; sp < 4; ++sp) {
                unsigned w[2];
                #pragma unroll
                for (int e = 0; e < 2; ++e) {
                    float v = (h < HD) ? W1[(size_t)(row0 + 2 * sp + e) * HD + h] : 0.0f;
                    w[e] = rne1(v);
                }
                pk[sp] = w[0] | (w[1] << 16);
            }
            Bl[u] = make_uint4(pk[0], pk[1], pk[2], pk[3]);
        }
        __syncthreads();

        const int mband = mg * 4 + (tid >> 6);   // 0..31
        const int b  = mband >> 3;
        const int tt = mband & 7;

        const float* __restrict__ Arow =
            hidden + (size_t)(b * TP1 + 1 + tt * 16 + col) * DD + (quad << 3);

        f32x4 a0 = (f32x4){0.f, 0.f, 0.f, 0.f};
        f32x4 a1 = (f32x4){0.f, 0.f, 0.f, 0.f};

        // software-pipelined A loads (1 step ahead)
        float4 px0 = *(const float4*)(Arow);
        float4 px1 = *(const float4*)(Arow + 4);
        #pragma unroll 4
        for (int ks = 0; ks < 24; ++ks) {
            float4 x0 = px0, x1 = px1;
            if (ks + 1 < 24) {
                px0 = *(const float4*)(Arow + (ks + 1) * 32);
                px1 = *(const float4*)(Arow + (ks + 1) * 32 + 4);
            }
            union { unsigned u[4]; s16x8 v; } af;
            af.u[0] = pkbf(x0.x, x0.y); af.u[1] = pkbf(x0.z, x0.w);
            af.u[2] = pkbf(x1.x, x1.y); af.u[3] = pkbf(x1.z, x1.w);
            union { uint4 q; s16x8 v; } bf0, bf1;
            bf0.q = Bl[ks * 64 + lane];
            bf1.q = Bl[1536 + ks * 64 + lane];
            a0 = __builtin_amdgcn_mfma_f32_16x16x32_bf16(af.v, bf0.v, a0, 0, 0, 0);
            a1 = __builtin_amdgcn_mfma_f32_16x16x32_bf16(af.v, bf1.v, a1, 0, 0, 0);
        }

        const int h = nt * 16 + col;
        if (h < HD) {
            const float bv = b1[h];
            #pragma unroll
            for (int r = 0; r < 4; ++r) {
                int t = tt * 16 + quad * 4 + r;
                size_t row = (size_t)(b * TT + t) * HP;
                P[row + h] = a0[r] + bv;
                Q[row + h] = a1[r];
            }
        }
    } else if (bx < 411) {
        int u = (bx - 392) * 256 + tid;
        if (u >= 4800) return;
        int nt = u / 1600;
        int rem = u - nt * 1600;
        int ks = rem >> 6;
        int ln = rem & 63;
        int kbase = ks * 32 + ((ln >> 4) << 3);
        int l = nt * 16 + (ln & 15);
        unsigned pk[4];
        #pragma unroll
        for (int sp = 0; sp < 4; ++sp) {
            unsigned w[2];
            #pragma unroll
            for (int e = 0; e < 2; ++e) {
                int k = kbase + 2 * sp + e;
                float v = (k < HD && l < LL) ? W2[k * LL + l] : 0.0f;
                w[e] = rne1(v);
            }
            pk[sp] = w[0] | (w[1] << 16);
        }
        ((uint4*)W2f)[u] = make_uint4(pk[0], pk[1], pk[2], pk[3]);
    } else if (bx == 411) {
        if (tid < 160) accum[tid] = 0.0f;
    } else {
        int u = (bx - 412) * 256 + tid;       // < 15360
        int row = u / 30;
        int h = HD + (u - row * 30);          // [770,800)
        Q[(size_t)row * HP + h] = 0.0f;
    }
}

// ====== kB (R11 structure): S-tile LDS MFMA, Q prefetch + W2f prefetch + lgkm barrier ======
__global__ __launch_bounds__(256) void kB(const float* __restrict__ P,
                                          const float* __restrict__ Q,
                                          const float* __restrict__ W1,
                                          const unsigned* __restrict__ W2f,
                                          const float* __restrict__ b2,
                                          const int* __restrict__ spans,
                                          const int* __restrict__ avail,
                                          float* __restrict__ out,
                                          float* __restrict__ accum) {
    __shared__ unsigned Sb[2][128 * 20];
    __shared__ float var[3 * HP];
    __shared__ int avi[TT];
    __shared__ float sred[192];

    const int i = blockIdx.x;
    const int b = blockIdx.y;
    const int tid = threadIdx.x;
    const int wave = tid >> 6;
    const int lane = tid & 63;

    const int start = spans[b * 2];
    const int end   = spans[b * 2 + 1];

    const int jS = tid >> 1;
    const int hh = (tid & 1) << 4;    // h-offset within 32-chunk: 0 or 16
    int indS;
    {
        bool isfull = (i == start) && (jS == end);
        bool inside = (start <= i) && (i <= jS) && (jS <= end) && !isfull;
        indS = isfull ? 2 : (inside ? 1 : 0);
    }

    {
        const float* Pi  = P + (size_t)(b * TT + i) * HP;
        const float* w1L = W1 + (size_t)2 * DD * HD;
        for (int h = tid; h < HP; h += 256) {
            float pv = (h < HD) ? Pi[h] : 0.0f;
            float wv = (h < HD) ? w1L[h] : 0.0f;
            var[h]        = pv;
            var[HP + h]   = pv + wv;
            var[2*HP + h] = pv + wv + wv;
        }
        if (tid < TT) avi[tid] = avail[i * TT + tid];
    }
    __syncthreads();   // var/avi visible before any pack reads them

    const float* Qj = Q + (size_t)(b * TT + jS) * HP;
    const float* vb = var + indS * HP;

    auto pack2 = [&](int c, int p, float4 qa, float4 qb, float4 qc, float4 qd) {
        const int h0 = c * 32 + hh;
        const float4* vp = (const float4*)(vb + h0);
        float4 v0 = vp[0], v1 = vp[1], v2 = vp[2], v3 = vp[3];
        float s0 = fmaxf(v0.x + qa.x, 0.f), s1 = fmaxf(v0.y + qa.y, 0.f);
        float s2 = fmaxf(v0.z + qa.z, 0.f), s3 = fmaxf(v0.w + qa.w, 0.f);
        float s4 = fmaxf(v1.x + qb.x, 0.f), s5 = fmaxf(v1.y + qb.y, 0.f);
        float s6 = fmaxf(v1.z + qb.z, 0.f), s7 = fmaxf(v1.w + qb.w, 0.f);
        float s8 = fmaxf(v2.x + qc.x, 0.f), s9 = fmaxf(v2.y + qc.y, 0.f);
        float sa = fmaxf(v2.z + qc.z, 0.f), sb_ = fmaxf(v2.w + qc.w, 0.f);
        float sc = fmaxf(v3.x + qd.x, 0.f), sd = fmaxf(v3.y + qd.y, 0.f);
        float se = fmaxf(v3.z + qd.z, 0.f), sf = fmaxf(v3.w + qd.w, 0.f);
        uint4* dst = (uint4*)(&Sb[p][jS * 20 + (hh >> 1)]);
        dst[0] = make_uint4(pkbf(s0,s1), pkbf(s2,s3), pkbf(s4,s5), pkbf(s6,s7));
        dst[1] = make_uint4(pkbf(s8,s9), pkbf(sa,sb_), pkbf(sc,sd), pkbf(se,sf));
    };

    f32x4 acc[2][3];
    #pragma unroll
    for (int mt = 0; mt < 2; ++mt)
        #pragma unroll
        for (int nt = 0; nt < 3; ++nt)
            acc[mt][nt] = (f32x4){0.f, 0.f, 0.f, 0.f};

    // prologue: pack chunk 0 (after barrier above), prefetch chunk-1 Q + chunk-0 W2f
    float4 ca, cb, cc, cd;
    union { uint4 q; s16x8 v; } wc0, wc1, wc2, wn0, wn1, wn2;
    {
        const float4* qp = (const float4*)(Qj + hh);
        float4 a0 = qp[0], a1 = qp[1], a2 = qp[2], a3 = qp[3];
        pack2(0, 0, a0, a1, a2, a3);
        const float4* qn = (const float4*)(Qj + 32 + hh);
        ca = qn[0]; cb = qn[1]; cc = qn[2]; cd = qn[3];
        wc0.q = ((const uint4*)W2f)[( 0) * 64 + lane];
        wc1.q = ((const uint4*)W2f)[(25) * 64 + lane];
        wc2.q = ((const uint4*)W2f)[(50) * 64 + lane];
    }
    ldsbar();

    const int arow0 = (wave * 32 + (lane & 15)) * 20 + ((lane >> 4) << 2);
    #pragma unroll
    for (int c = 0; c < 25; ++c) {
        const int p = c & 1;
        // prefetch next chunk's W2f fragments
        if (c + 1 < 25) {
            wn0.q = ((const uint4*)W2f)[( 0 + c + 1) * 64 + lane];
            wn1.q = ((const uint4*)W2f)[(25 + c + 1) * 64 + lane];
            wn2.q = ((const uint4*)W2f)[(50 + c + 1) * 64 + lane];
        }
        s16x8 af0 = *(const s16x8*)(&Sb[p][arow0]);
        s16x8 af1 = *(const s16x8*)(&Sb[p][arow0 + 16 * 20]);
        if (c + 1 < 25) {
            float4 fa = ca, fb = cb, fc = cc, fd = cd;
            if (c + 2 < 25) {
                const float4* qn = (const float4*)(Qj + (c + 2) * 32 + hh);
                ca = qn[0]; cb = qn[1]; cc = qn[2]; cd = qn[3];
            }
            pack2(c + 1, p ^ 1, fa, fb, fc, fd);
        }
        acc[0][0] = __builtin_amdgcn_mfma_f32_16x16x32_bf16(af0, wc0.v, acc[0][0], 0, 0, 0);
        acc[0][1] = __builtin_amdgcn_mfma_f32_16x16x32_bf16(af0, wc1.v, acc[0][1], 0, 0, 0);
        acc[0][2] = __builtin_amdgcn_mfma_f32_16x16x32_bf16(af0, wc2.v, acc[0][2], 0, 0, 0);
        acc[1][0] = __builtin_amdgcn_mfma_f32_16x16x32_bf16(af1, wc0.v, acc[1][0], 0, 0, 0);
        acc[1][1] = __builtin_amdgcn_mfma_f32_16x16x32_bf16(af1, wc1.v, acc[1][1], 0, 0, 0);
        acc[1][2] = __builtin_amdgcn_mfma_f32_16x16x32_bf16(af1, wc2.v, acc[1][2], 0, 0, 0);
        wc0 = wn0; wc1 = wn1; wc2 = wn2;
        ldsbar();   // lgkm-only: Sb writes visible; global loads stay in flight
    }

    float bias[3];
    #pragma unroll
    for (int nt = 0; nt < 3; ++nt) {
        int l = nt * 16 + (lane & 15);
        bias[nt] = (l < LL) ? b2[l] : 0.0f;
    }
    const int jr0 = wave * 32 + ((lane >> 4) << 2);
    float sE[3] = {0.f, 0.f, 0.f};
    #pragma unroll
    for (int mt = 0; mt < 2; ++mt) {
        #pragma unroll
        for (int r = 0; r < 4; ++r) {
            int j = jr0 + mt * 16 + r;
            bool msk = avi[j] >= 1;
            size_t rowoff = ((size_t)(b * (TT * TT) + i * TT + j)) * LL;
            #pragma unroll
            for (int nt = 0; nt < 3; ++nt) {
                int l = nt * 16 + (lane & 15);
                if (l < LL) {
                    float val = msk ? (acc[mt][nt][r] + bias[nt]) : 0.0f;
                    out[rowoff + l] = val;
                    sE[nt] += __expf(val);
                }
            }
        }
    }
    #pragma unroll
    for (int nt = 0; nt < 3; ++nt) {
        float v = sE[nt];
        v += __shfl_xor(v, 16);
        v += __shfl_xor(v, 32);
        if (lane < 16) sred[wave * 48 + nt * 16 + lane] = v;
    }
    __syncthreads();
    if (tid < 48) {
        float t4 = sred[tid] + sred[48 + tid] + sred[96 + tid] + sred[144 + tid];
        if (tid < LL) atomicAdd(&accum[b * LL + tid], t4);
    }
}

// ================= kD: out -= log(denom) =================
__global__ __launch_bounds__(256) void kD(float* __restrict__ out,
                                          const float* __restrict__ accum) {
    const int idx = blockIdx.x * 256 + threadIdx.x;
    const int e = idx * 4;
    const int b = e / (TT * TT * LL);
    const int l = e % LL;
    float4 v = ((float4*)out)[idx];
    const float* ac = accum + b * LL + l;
    v.x -= __logf(ac[0]); v.y -= __logf(ac[1]);
    v.z -= __logf(ac[2]); v.w -= __logf(ac[3]);
    ((float4*)out)[idx] = v;
}

extern "C" void kernel_launch(void* const* d_in, const int* in_sizes, int n_in,
                              void* d_out, int out_size, void* d_ws, size_t ws_size,
                              hipStream_t stream) {
    const float* hidden = (const float*)d_in[0];
    const float* W1     = (const float*)d_in[1];
    const float* b1     = (const float*)d_in[2];
    const float* W2     = (const float*)d_in[3];
    const float* b2     = (const float*)d_in[4];
    const int*   spans  = (const int*)d_in[5];
    const int*   avail  = (const int*)d_in[6];
    float* out = (float*)d_out;
    float* ws  = (float*)d_ws;

    float*    P     = ws + P_OFF;
    float*    Q     = ws + Q_OFF;
    unsigned* W2f   = (unsigned*)(ws + W2F_OFF);
    float*    accum = ws + ACC_OFF;

    kA <<<dim3(472),    dim3(256), 0, stream>>>(hidden, W1, W2, b1, P, Q, W2f, accum);
    kB <<<dim3(TT, BB), dim3(256), 0, stream>>>(P, Q, W1, W2f, b2, spans, avail, out, accum);
    kD <<<dim3(2560),   dim3(256), 0, stream>>>(out, accum);
}

// Round 14
// 123.663 us; speedup vs baseline: 1.0175x; 1.0008x over previous
//
#include <hip/hip_runtime.h>
#include <math.h>

#define BB 4
#define TT 128
#define DD 768
#define HD 770
#define HP 800
#define LL 40
#define TP1 129
#define VS 812   // var row stride: 812 mod 32 = 12 -> variant rows on distinct bank groups

typedef __attribute__((ext_vector_type(8))) short s16x8;
typedef __attribute__((ext_vector_type(4))) float f32x4;

// ws float offsets
#define P_OFF   0
#define Q_OFF   409600          // 512*800
#define W2F_OFF 819200          // 4800 uint4 = 19200 u32
#define ACC_OFF 838400          // 160 floats

__device__ __forceinline__ unsigned pkbf(float a, float b) {
    unsigned ua = __float_as_uint(a);
    unsigned ub = __float_as_uint(b);
    return ((ua + 0x8000u) >> 16) | ((ub + 0x8000u) & 0xffff0000u);
}
__device__ __forceinline__ unsigned rne1(float v) {
    unsigned x = __float_as_uint(v);
    return (x + 0x7fffu + ((x >> 16) & 1u)) >> 16;
}
// lgkm-only barrier: ds ops drained, global loads stay in flight
__device__ __forceinline__ void ldsbar() {
    asm volatile("s_waitcnt lgkmcnt(0)\n\ts_barrier" ::: "memory");
}

// ====== kA (R10-proven, exact): fused prep + X@{W1a,W1b} GEMM, B-frags in LDS ======
__global__ __launch_bounds__(256) void kA(const float* __restrict__ hidden,
                                          const float* __restrict__ W1,
                                          const float* __restrict__ W2,
                                          const float* __restrict__ b1,
                                          float* __restrict__ P,
                                          float* __restrict__ Q,
                                          unsigned* __restrict__ W2f,
                                          float* __restrict__ accum) {
    __shared__ uint4 Bl[3072];   // 48 KB: [half 0..1][ks 0..23][lane 0..63]
    const int bx  = blockIdx.x;
    const int tid = threadIdx.x;

    if (bx < 392) {
        const int nt = bx / 8;          // 0..48
        const int mg = bx - nt * 8;     // 0..7
        const int lane = tid & 63;
        const int col  = lane & 15;
        const int quad = lane >> 4;

        for (int u = tid; u < 3072; u += 256) {
            int half = u / 1536;
            int rem  = u - half * 1536;
            int ks = rem >> 6;
            int ln = rem & 63;
            int kbase = ks * 32 + ((ln >> 4) << 3);
            int h = nt * 16 + (ln & 15);
            int row0 = half * DD + kbase;
            unsigned pk[4];
            #pragma unroll
            for (int sp = 0; sp < 4; ++sp) {
                unsigned w[2];
                #pragma unroll
                for (int e = 0; e < 2; ++e) {
                    float v = (h < HD) ? W1[(size_t)(row0 + 2 * sp + e) * HD + h] : 0.0f;
                    w[e] = rne1(v);
                }
                pk[sp] = w[0] | (w[1] << 16);
            }
            Bl[u] = make_uint4(pk[0], pk[1], pk[2], pk[3]);
        }
        __syncthreads();

        const int mband = mg * 4 + (tid >> 6);   // 0..31
        const int b  = mband >> 3;
        const int tt = mband & 7;

        const float* __restrict__ Arow =
            hidden + (size_t)(b * TP1 + 1 + tt * 16 + col) * DD + (quad << 3);

        f32x4 a0 = (f32x4){0.f, 0.f, 0.f, 0.f};
        f32x4 a1 = (f32x4){0.f, 0.f, 0.f, 0.f};

        #pragma unroll 4
        for (int ks = 0; ks < 24; ++ks) {
            float4 x0 = *(const float4*)(Arow + ks * 32);
            float4 x1 = *(const float4*)(Arow + ks * 32 + 4);
            union { unsigned u[4]; s16x8 v; } af;
            af.u[0] = pkbf(x0.x, x0.y); af.u[1] = pkbf(x0.z, x0.w);
            af.u[2] = pkbf(x1.x, x1.y); af.u[3] = pkbf(x1.z, x1.w);
            union { uint4 q; s16x8 v; } bf0, bf1;
            bf0.q = Bl[ks * 64 + lane];
            bf1.q = Bl[1536 + ks * 64 + lane];
            a0 = __builtin_amdgcn_mfma_f32_16x16x32_bf16(af.v, bf0.v, a0, 0, 0, 0);
            a1 = __builtin_amdgcn_mfma_f32_16x16x32_bf16(af.v, bf1.v, a1, 0, 0, 0);
        }

        const int h = nt * 16 + col;
        if (h < HD) {
            const float bv = b1[h];
            #pragma unroll
            for (int r = 0; r < 4; ++r) {
                int t = tt * 16 + quad * 4 + r;
                size_t row = (size_t)(b * TT + t) * HP;
                P[row + h] = a0[r] + bv;
                Q[row + h] = a1[r];
            }
        }
    } else if (bx < 411) {
        int u = (bx - 392) * 256 + tid;
        if (u >= 4800) return;
        int nt = u / 1600;
        int rem = u - nt * 1600;
        int ks = rem >> 6;
        int ln = rem & 63;
        int kbase = ks * 32 + ((ln >> 4) << 3);
        int l = nt * 16 + (ln & 15);
        unsigned pk[4];
        #pragma unroll
        for (int sp = 0; sp < 4; ++sp) {
            unsigned w[2];
            #pragma unroll
            for (int e = 0; e < 2; ++e) {
                int k = kbase + 2 * sp + e;
                float v = (k < HD && l < LL) ? W2[k * LL + l] : 0.0f;
                w[e] = rne1(v);
            }
            pk[sp] = w[0] | (w[1] << 16);
        }
        ((uint4*)W2f)[u] = make_uint4(pk[0], pk[1], pk[2], pk[3]);
    } else if (bx == 411) {
        if (tid < 160) accum[tid] = 0.0f;
    } else {
        int u = (bx - 412) * 256 + tid;       // < 15360
        int row = u / 30;
        int h = HD + (u - row * 30);          // [770,800)
        Q[(size_t)row * HP + h] = 0.0f;
    }
}

// ====== kB: S-tile LDS MFMA; Q 2-deep prefetch; lgkm-only barrier; VS=812 var ======
__global__ __launch_bounds__(256) void kB(const float* __restrict__ P,
                                          const float* __restrict__ Q,
                                          const float* __restrict__ W1,
                                          const unsigned* __restrict__ W2f,
                                          const float* __restrict__ b2,
                                          const int* __restrict__ spans,
                                          const int* __restrict__ avail,
                                          float* __restrict__ out,
                                          float* __restrict__ accum) {
    __shared__ unsigned Sb[2][128 * 20];
    __shared__ float var[3 * VS];
    __shared__ int avi[TT];
    __shared__ float sred[192];

    const int i = blockIdx.x;
    const int b = blockIdx.y;
    const int tid = threadIdx.x;
    const int wave = tid >> 6;
    const int lane = tid & 63;

    const int start = spans[b * 2];
    const int end   = spans[b * 2 + 1];

    const int jS = tid >> 1;
    const int hh = (tid & 1) << 4;    // h-offset within 32-chunk: 0 or 16
    int indS;
    {
        bool isfull = (i == start) && (jS == end);
        bool inside = (start <= i) && (i <= jS) && (jS <= end) && !isfull;
        indS = isfull ? 2 : (inside ? 1 : 0);
    }

    {
        const float* Pi  = P + (size_t)(b * TT + i) * HP;
        const float* w1L = W1 + (size_t)2 * DD * HD;
        for (int h = tid; h < HP; h += 256) {
            float pv = (h < HD) ? Pi[h] : 0.0f;
            float wv = (h < HD) ? w1L[h] : 0.0f;
            var[h]          = pv;
            var[VS + h]     = pv + wv;
            var[2 * VS + h] = pv + wv + wv;
        }
        if (tid < TT) avi[tid] = avail[i * TT + tid];
    }
    __syncthreads();   // var/avi visible before any pack reads them

    const float* Qj = Q + (size_t)(b * TT + jS) * HP;
    const float* vb = var + indS * VS;

    auto pack2 = [&](int c, int p, float4 qa, float4 qb, float4 qc, float4 qd) {
        const int h0 = c * 32 + hh;
        const float4* vp = (const float4*)(vb + h0);
        float4 v0 = vp[0], v1 = vp[1], v2 = vp[2], v3 = vp[3];
        float s0 = fmaxf(v0.x + qa.x, 0.f), s1 = fmaxf(v0.y + qa.y, 0.f);
        float s2 = fmaxf(v0.z + qa.z, 0.f), s3 = fmaxf(v0.w + qa.w, 0.f);
        float s4 = fmaxf(v1.x + qb.x, 0.f), s5 = fmaxf(v1.y + qb.y, 0.f);
        float s6 = fmaxf(v1.z + qb.z, 0.f), s7 = fmaxf(v1.w + qb.w, 0.f);
        float s8 = fmaxf(v2.x + qc.x, 0.f), s9 = fmaxf(v2.y + qc.y, 0.f);
        float sa = fmaxf(v2.z + qc.z, 0.f), sb_ = fmaxf(v2.w + qc.w, 0.f);
        float sc = fmaxf(v3.x + qd.x, 0.f), sd = fmaxf(v3.y + qd.y, 0.f);
        float se = fmaxf(v3.z + qd.z, 0.f), sf = fmaxf(v3.w + qd.w, 0.f);
        uint4* dst = (uint4*)(&Sb[p][jS * 20 + (hh >> 1)]);
        dst[0] = make_uint4(pkbf(s0,s1), pkbf(s2,s3), pkbf(s4,s5), pkbf(s6,s7));
        dst[1] = make_uint4(pkbf(s8,s9), pkbf(sa,sb_), pkbf(sc,sd), pkbf(se,sf));
    };

    f32x4 acc[2][3];
    #pragma unroll
    for (int mt = 0; mt < 2; ++mt)
        #pragma unroll
        for (int nt = 0; nt < 3; ++nt)
            acc[mt][nt] = (f32x4){0.f, 0.f, 0.f, 0.f};

    // prologue: pack chunk 0, prefetch chunk-1 Q
    float4 ca, cb, cc, cd;
    {
        const float4* qp = (const float4*)(Qj + hh);
        float4 a0 = qp[0], a1 = qp[1], a2 = qp[2], a3 = qp[3];
        pack2(0, 0, a0, a1, a2, a3);
        const float4* qn = (const float4*)(Qj + 32 + hh);
        ca = qn[0]; cb = qn[1]; cc = qn[2]; cd = qn[3];
    }
    ldsbar();

    const int arow0 = (wave * 32 + (lane & 15)) * 20 + ((lane >> 4) << 2);
    #pragma unroll
    for (int c = 0; c < 25; ++c) {
        const int p = c & 1;
        s16x8 bf0 = *(const s16x8*)((const unsigned*)W2f + (( 0 + c) * 64 + lane) * 4);
        s16x8 bf1 = *(const s16x8*)((const unsigned*)W2f + ((25 + c) * 64 + lane) * 4);
        s16x8 bf2 = *(const s16x8*)((const unsigned*)W2f + ((50 + c) * 64 + lane) * 4);
        s16x8 af0 = *(const s16x8*)(&Sb[p][arow0]);
        s16x8 af1 = *(const s16x8*)(&Sb[p][arow0 + 16 * 20]);
        if (c + 1 < 25) {
            float4 fa = ca, fb = cb, fc = cc, fd = cd;
            if (c + 2 < 25) {
                const float4* qn = (const float4*)(Qj + (c + 2) * 32 + hh);
                ca = qn[0]; cb = qn[1]; cc = qn[2]; cd = qn[3];
            }
            pack2(c + 1, p ^ 1, fa, fb, fc, fd);
        }
        acc[0][0] = __builtin_amdgcn_mfma_f32_16x16x32_bf16(af0, bf0, acc[0][0], 0, 0, 0);
        acc[0][1] = __builtin_amdgcn_mfma_f32_16x16x32_bf16(af0, bf1, acc[0][1], 0, 0, 0);
        acc[0][2] = __builtin_amdgcn_mfma_f32_16x16x32_bf16(af0, bf2, acc[0][2], 0, 0, 0);
        acc[1][0] = __builtin_amdgcn_mfma_f32_16x16x32_bf16(af1, bf0, acc[1][0], 0, 0, 0);
        acc[1][1] = __builtin_amdgcn_mfma_f32_16x16x32_bf16(af1, bf1, acc[1][1], 0, 0, 0);
        acc[1][2] = __builtin_amdgcn_mfma_f32_16x16x32_bf16(af1, bf2, acc[1][2], 0, 0, 0);
        ldsbar();   // lgkm-only: Sb writes visible; global loads stay in flight
    }

    float bias[3];
    #pragma unroll
    for (int nt = 0; nt < 3; ++nt) {
        int l = nt * 16 + (lane & 15);
        bias[nt] = (l < LL) ? b2[l] : 0.0f;
    }
    const int jr0 = wave * 32 + ((lane >> 4) << 2);
    float sE[3] = {0.f, 0.f, 0.f};
    #pragma unroll
    for (int mt = 0; mt < 2; ++mt) {
        #pragma unroll
        for (int r = 0; r < 4; ++r) {
            int j = jr0 + mt * 16 + r;
            bool msk = avi[j] >= 1;
            size_t rowoff = ((size_t)(b * (TT * TT) + i * TT + j)) * LL;
            #pragma unroll
            for (int nt = 0; nt < 3; ++nt) {
                int l = nt * 16 + (lane & 15);
                if (l < LL) {
                    float val = msk ? (acc[mt][nt][r] + bias[nt]) : 0.0f;
                    out[rowoff + l] = val;
                    sE[nt] += __expf(val);
                }
            }
        }
    }
    #pragma unroll
    for (int nt = 0; nt < 3; ++nt) {
        float v = sE[nt];
        v += __shfl_xor(v, 16);
        v += __shfl_xor(v, 32);
        if (lane < 16) sred[wave * 48 + nt * 16 + lane] = v;
    }
    __syncthreads();
    if (tid < 48) {
        float t4 = sred[tid] + sred[48 + tid] + sred[96 + tid] + sred[144 + tid];
        if (tid < LL) atomicAdd(&accum[b * LL + tid], t4);
    }
}

// ================= kD: out -= log(denom) =================
__global__ __launch_bounds__(256) void kD(float* __restrict__ out,
                                          const float* __restrict__ accum) {
    const int idx = blockIdx.x * 256 + threadIdx.x;
    const int e = idx * 4;
    const int b = e / (TT * TT * LL);
    const int l = e % LL;
    float4 v = ((float4*)out)[idx];
    const float* ac = accum + b * LL + l;
    v.x -= __logf(ac[0]); v.y -= __logf(ac[1]);
    v.z -= __logf(ac[2]); v.w -= __logf(ac[3]);
    ((float4*)out)[idx] = v;
}

extern "C" void kernel_launch(void* const* d_in, const int* in_sizes, int n_in,
                              void* d_out, int out_size, void* d_ws, size_t ws_size,
                              hipStream_t stream) {
    const float* hidden = (const float*)d_in[0];
    const float* W1     = (const float*)d_in[1];
    const float* b1     = (const float*)d_in[2];
    const float* W2     = (const float*)d_in[3];
    const float* b2     = (const float*)d_in[4];
    const int*   spans  = (const int*)d_in[5];
    const int*   avail  = (const int*)d_in[6];
    float* out = (float*)d_out;
    float* ws  = (float*)d_ws;

    float*    P     = ws + P_OFF;
    float*    Q     = ws + Q_OFF;
    unsigned* W2f   = (unsigned*)(ws + W2F_OFF);
    float*    accum = ws + ACC_OFF;

    kA <<<dim3(472),    dim3(256), 0, stream>>>(hidden, W1, W2, b1, P, Q, W2f, accum);
    kB <<<dim3(TT, BB), dim3(256), 0, stream>>>(P, Q, W1, W2f, b2, spans, avail, out, accum);
    kD <<<dim3(2560),   dim3(256), 0, stream>>>(out, accum);
}

// Round 15
// 122.693 us; speedup vs baseline: 1.0255x; 1.0079x over previous
//
#include <hip/hip_runtime.h>
#include <math.h>

#define BB 4
#define TT 128
#define DD 768
#define HD 770
#define HP 800
#define LL 40
#define TP1 129
#define VS 812   // var row stride: 812 mod 32 = 12 -> variant rows on distinct bank groups

typedef __attribute__((ext_vector_type(8))) short s16x8;
typedef __attribute__((ext_vector_type(4))) float f32x4;

// ws float offsets
#define P_OFF   0
#define Q_OFF   409600          // 512*800
#define W2F_OFF 819200          // 4800 uint4 = 19200 u32
#define ACC_OFF 838400          // 160 floats

__device__ __forceinline__ unsigned pkbf(float a, float b) {
    unsigned ua = __float_as_uint(a);
    unsigned ub = __float_as_uint(b);
    return ((ua + 0x8000u) >> 16) | ((ub + 0x8000u) & 0xffff0000u);
}
__device__ __forceinline__ unsigned rne1(float v) {
    unsigned x = __float_as_uint(v);
    return (x + 0x7fffu + ((x >> 16) & 1u)) >> 16;
}
// intra-wave LDS ordering only — NO s_barrier (kB K-loop is wave-closed)
__device__ __forceinline__ void ldswait() {
    asm volatile("s_waitcnt lgkmcnt(0)" ::: "memory");
}

// ====== kA (R10-proven, exact): fused prep + X@{W1a,W1b} GEMM, B-frags in LDS ======
__global__ __launch_bounds__(256) void kA(const float* __restrict__ hidden,
                                          const float* __restrict__ W1,
                                          const float* __restrict__ W2,
                                          const float* __restrict__ b1,
                                          float* __restrict__ P,
                                          float* __restrict__ Q,
                                          unsigned* __restrict__ W2f,
                                          float* __restrict__ accum) {
    __shared__ uint4 Bl[3072];   // 48 KB: [half 0..1][ks 0..23][lane 0..63]
    const int bx  = blockIdx.x;
    const int tid = threadIdx.x;

    if (bx < 392) {
        const int nt = bx / 8;          // 0..48
        const int mg = bx - nt * 8;     // 0..7
        const int lane = tid & 63;
        const int col  = lane & 15;
        const int quad = lane >> 4;

        for (int u = tid; u < 3072; u += 256) {
            int half = u / 1536;
            int rem  = u - half * 1536;
            int ks = rem >> 6;
            int ln = rem & 63;
            int kbase = ks * 32 + ((ln >> 4) << 3);
            int h = nt * 16 + (ln & 15);
            int row0 = half * DD + kbase;
            unsigned pk[4];
            #pragma unroll
            for (int sp = 0; sp < 4; ++sp) {
                unsigned w[2];
                #pragma unroll
                for (int e = 0; e < 2; ++e) {
                    float v = (h < HD) ? W1[(size_t)(row0 + 2 * sp + e) * HD + h] : 0.0f;
                    w[e] = rne1(v);
                }
                pk[sp] = w[0] | (w[1] << 16);
            }
            Bl[u] = make_uint4(pk[0], pk[1], pk[2], pk[3]);
        }
        __syncthreads();

        const int mband = mg * 4 + (tid >> 6);   // 0..31
        const int b  = mband >> 3;
        const int tt = mband & 7;

        const float* __restrict__ Arow =
            hidden + (size_t)(b * TP1 + 1 + tt * 16 + col) * DD + (quad << 3);

        f32x4 a0 = (f32x4){0.f, 0.f, 0.f, 0.f};
        f32x4 a1 = (f32x4){0.f, 0.f, 0.f, 0.f};

        #pragma unroll 4
        for (int ks = 0; ks < 24; ++ks) {
            float4 x0 = *(const float4*)(Arow + ks * 32);
            float4 x1 = *(const float4*)(Arow + ks * 32 + 4);
            union { unsigned u[4]; s16x8 v; } af;
            af.u[0] = pkbf(x0.x, x0.y); af.u[1] = pkbf(x0.z, x0.w);
            af.u[2] = pkbf(x1.x, x1.y); af.u[3] = pkbf(x1.z, x1.w);
            union { uint4 q; s16x8 v; } bf0, bf1;
            bf0.q = Bl[ks * 64 + lane];
            bf1.q = Bl[1536 + ks * 64 + lane];
            a0 = __builtin_amdgcn_mfma_f32_16x16x32_bf16(af.v, bf0.v, a0, 0, 0, 0);
            a1 = __builtin_amdgcn_mfma_f32_16x16x32_bf16(af.v, bf1.v, a1, 0, 0, 0);
        }

        const int h = nt * 16 + col;
        if (h < HD) {
            const float bv = b1[h];
            #pragma unroll
            for (int r = 0; r < 4; ++r) {
                int t = tt * 16 + quad * 4 + r;
                size_t row = (size_t)(b * TT + t) * HP;
                P[row + h] = a0[r] + bv;
                Q[row + h] = a1[r];
            }
        }
    } else if (bx < 411) {
        int u = (bx - 392) * 256 + tid;
        if (u >= 4800) return;
        int nt = u / 1600;
        int rem = u - nt * 1600;
        int ks = rem >> 6;
        int ln = rem & 63;
        int kbase = ks * 32 + ((ln >> 4) << 3);
        int l = nt * 16 + (ln & 15);
        unsigned pk[4];
        #pragma unroll
        for (int sp = 0; sp < 4; ++sp) {
            unsigned w[2];
            #pragma unroll
            for (int e = 0; e < 2; ++e) {
                int k = kbase + 2 * sp + e;
                float v = (k < HD && l < LL) ? W2[k * LL + l] : 0.0f;
                w[e] = rne1(v);
            }
            pk[sp] = w[0] | (w[1] << 16);
        }
        ((uint4*)W2f)[u] = make_uint4(pk[0], pk[1], pk[2], pk[3]);
    } else if (bx == 411) {
        if (tid < 160) accum[tid] = 0.0f;
    } else {
        int u = (bx - 412) * 256 + tid;       // < 15360
        int row = u / 30;
        int h = HD + (u - row * 30);          // [770,800)
        Q[(size_t)row * HP + h] = 0.0f;
    }
}

// ====== kB: wave-closed S-tile MFMA — NO in-loop s_barrier; Q 2-deep prefetch ======
__global__ __launch_bounds__(256) void kB(const float* __restrict__ P,
                                          const float* __restrict__ Q,
                                          const float* __restrict__ W1,
                                          const unsigned* __restrict__ W2f,
                                          const float* __restrict__ b2,
                                          const int* __restrict__ spans,
                                          const int* __restrict__ avail,
                                          float* __restrict__ out,
                                          float* __restrict__ accum) {
    __shared__ unsigned Sb[2][128 * 20];
    __shared__ float var[3 * VS];
    __shared__ int avi[TT];
    __shared__ float sred[192];

    const int i = blockIdx.x;
    const int b = blockIdx.y;
    const int tid = threadIdx.x;
    const int wave = tid >> 6;
    const int lane = tid & 63;

    const int start = spans[b * 2];
    const int end   = spans[b * 2 + 1];

    const int jS = tid >> 1;          // wave w's threads cover rows [32w, 32w+32)
    const int hh = (tid & 1) << 4;    // h-offset within 32-chunk: 0 or 16
    int indS;
    {
        bool isfull = (i == start) && (jS == end);
        bool inside = (start <= i) && (i <= jS) && (jS <= end) && !isfull;
        indS = isfull ? 2 : (inside ? 1 : 0);
    }

    {
        const float* Pi  = P + (size_t)(b * TT + i) * HP;
        const float* w1L = W1 + (size_t)2 * DD * HD;
        for (int h = tid; h < HP; h += 256) {
            float pv = (h < HD) ? Pi[h] : 0.0f;
            float wv = (h < HD) ? w1L[h] : 0.0f;
            var[h]          = pv;
            var[VS + h]     = pv + wv;
            var[2 * VS + h] = pv + wv + wv;
        }
        if (tid < TT) avi[tid] = avail[i * TT + tid];
    }
    __syncthreads();   // var/avi visible to all waves; ONLY cross-wave barrier before epilogue

    const float* Qj = Q + (size_t)(b * TT + jS) * HP;
    const float* vb = var + indS * VS;

    auto pack2 = [&](int c, int p, float4 qa, float4 qb, float4 qc, float4 qd) {
        const int h0 = c * 32 + hh;
        const float4* vp = (const float4*)(vb + h0);
        float4 v0 = vp[0], v1 = vp[1], v2 = vp[2], v3 = vp[3];
        float s0 = fmaxf(v0.x + qa.x, 0.f), s1 = fmaxf(v0.y + qa.y, 0.f);
        float s2 = fmaxf(v0.z + qa.z, 0.f), s3 = fmaxf(v0.w + qa.w, 0.f);
        float s4 = fmaxf(v1.x + qb.x, 0.f), s5 = fmaxf(v1.y + qb.y, 0.f);
        float s6 = fmaxf(v1.z + qb.z, 0.f), s7 = fmaxf(v1.w + qb.w, 0.f);
        float s8 = fmaxf(v2.x + qc.x, 0.f), s9 = fmaxf(v2.y + qc.y, 0.f);
        float sa = fmaxf(v2.z + qc.z, 0.f), sb_ = fmaxf(v2.w + qc.w, 0.f);
        float sc = fmaxf(v3.x + qd.x, 0.f), sd = fmaxf(v3.y + qd.y, 0.f);
        float se = fmaxf(v3.z + qd.z, 0.f), sf = fmaxf(v3.w + qd.w, 0.f);
        uint4* dst = (uint4*)(&Sb[p][jS * 20 + (hh >> 1)]);
        dst[0] = make_uint4(pkbf(s0,s1), pkbf(s2,s3), pkbf(s4,s5), pkbf(s6,s7));
        dst[1] = make_uint4(pkbf(s8,s9), pkbf(sa,sb_), pkbf(sc,sd), pkbf(se,sf));
    };

    f32x4 acc[2][3];
    #pragma unroll
    for (int mt = 0; mt < 2; ++mt)
        #pragma unroll
        for (int nt = 0; nt < 3; ++nt)
            acc[mt][nt] = (f32x4){0.f, 0.f, 0.f, 0.f};

    // prologue: pack chunk 0, prefetch chunk-1 Q
    float4 ca, cb, cc, cd;
    {
        const float4* qp = (const float4*)(Qj + hh);
        float4 a0 = qp[0], a1 = qp[1], a2 = qp[2], a3 = qp[3];
        pack2(0, 0, a0, a1, a2, a3);
        const float4* qn = (const float4*)(Qj + 32 + hh);
        ca = qn[0]; cb = qn[1]; cc = qn[2]; cd = qn[3];
    }
    ldswait();   // this wave's ds_writes drained before its ds_reads

    // consumer reads rows [32*wave, 32*wave+32) — exactly what this wave's threads wrote
    const int arow0 = (wave * 32 + (lane & 15)) * 20 + ((lane >> 4) << 2);
    #pragma unroll
    for (int c = 0; c < 25; ++c) {
        const int p = c & 1;
        s16x8 bf0 = *(const s16x8*)((const unsigned*)W2f + (( 0 + c) * 64 + lane) * 4);
        s16x8 bf1 = *(const s16x8*)((const unsigned*)W2f + ((25 + c) * 64 + lane) * 4);
        s16x8 bf2 = *(const s16x8*)((const unsigned*)W2f + ((50 + c) * 64 + lane) * 4);
        s16x8 af0 = *(const s16x8*)(&Sb[p][arow0]);
        s16x8 af1 = *(const s16x8*)(&Sb[p][arow0 + 16 * 20]);
        if (c + 1 < 25) {
            float4 fa = ca, fb = cb, fc = cc, fd = cd;
            if (c + 2 < 25) {
                const float4* qn = (const float4*)(Qj + (c + 2) * 32 + hh);
                ca = qn[0]; cb = qn[1]; cc = qn[2]; cd = qn[3];
            }
            pack2(c + 1, p ^ 1, fa, fb, fc, fd);
        }
        acc[0][0] = __builtin_amdgcn_mfma_f32_16x16x32_bf16(af0, bf0, acc[0][0], 0, 0, 0);
        acc[0][1] = __builtin_amdgcn_mfma_f32_16x16x32_bf16(af0, bf1, acc[0][1], 0, 0, 0);
        acc[0][2] = __builtin_amdgcn_mfma_f32_16x16x32_bf16(af0, bf2, acc[0][2], 0, 0, 0);
        acc[1][0] = __builtin_amdgcn_mfma_f32_16x16x32_bf16(af1, bf0, acc[1][0], 0, 0, 0);
        acc[1][1] = __builtin_amdgcn_mfma_f32_16x16x32_bf16(af1, bf1, acc[1][1], 0, 0, 0);
        acc[1][2] = __builtin_amdgcn_mfma_f32_16x16x32_bf16(af1, bf2, acc[1][2], 0, 0, 0);
        ldswait();   // intra-wave write->read ordering; waves free-run
    }

    float bias[3];
    #pragma unroll
    for (int nt = 0; nt < 3; ++nt) {
        int l = nt * 16 + (lane & 15);
        bias[nt] = (l < LL) ? b2[l] : 0.0f;
    }
    const int jr0 = wave * 32 + ((lane >> 4) << 2);
    float sE[3] = {0.f, 0.f, 0.f};
    #pragma unroll
    for (int mt = 0; mt < 2; ++mt) {
        #pragma unroll
        for (int r = 0; r < 4; ++r) {
            int j = jr0 + mt * 16 + r;
            bool msk = avi[j] >= 1;
            size_t rowoff = ((size_t)(b * (TT * TT) + i * TT + j)) * LL;
            #pragma unroll
            for (int nt = 0; nt < 3; ++nt) {
                int l = nt * 16 + (lane & 15);
                if (l < LL) {
                    float val = msk ? (acc[mt][nt][r] + bias[nt]) : 0.0f;
                    out[rowoff + l] = val;
                    sE[nt] += __expf(val);
                }
            }
        }
    }
    #pragma unroll
    for (int nt = 0; nt < 3; ++nt) {
        float v = sE[nt];
        v += __shfl_xor(v, 16);
        v += __shfl_xor(v, 32);
        if (lane < 16) sred[wave * 48 + nt * 16 + lane] = v;
    }
    __syncthreads();
    if (tid < 48) {
        float t4 = sred[tid] + sred[48 + tid] + sred[96 + tid] + sred[144 + tid];
        if (tid < LL) atomicAdd(&accum[b * LL + tid], t4);
    }
}

// ================= kD: out -= log(denom) =================
__global__ __launch_bounds__(256) void kD(float* __restrict__ out,
                                          const float* __restrict__ accum) {
    const int idx = blockIdx.x * 256 + threadIdx.x;
    const int e = idx * 4;
    const int b = e / (TT * TT * LL);
    const int l = e % LL;
    float4 v = ((float4*)out)[idx];
    const float* ac = accum + b * LL + l;
    v.x -= __logf(ac[0]); v.y -= __logf(ac[1]);
    v.z -= __logf(ac[2]); v.w -= __logf(ac[3]);
    ((float4*)out)[idx] = v;
}

extern "C" void kernel_launch(void* const* d_in, const int* in_sizes, int n_in,
                              void* d_out, int out_size, void* d_ws, size_t ws_size,
                              hipStream_t stream) {
    const float* hidden = (const float*)d_in[0];
    const float* W1     = (const float*)d_in[1];
    const float* b1     = (const float*)d_in[2];
    const float* W2     = (const float*)d_in[3];
    const float* b2     = (const float*)d_in[4];
    const int*   spans  = (const int*)d_in[5];
    const int*   avail  = (const int*)d_in[6];
    float* out = (float*)d_out;
    float* ws  = (float*)d_ws;

    float*    P     = ws + P_OFF;
    float*    Q     = ws + Q_OFF;
    unsigned* W2f   = (unsigned*)(ws + W2F_OFF);
    float*    accum = ws + ACC_OFF;

    kA <<<dim3(472),    dim3(256), 0, stream>>>(hidden, W1, W2, b1, P, Q, W2f, accum);
    kB <<<dim3(TT, BB), dim3(256), 0, stream>>>(P, Q, W1, W2f, b2, spans, avail, out, accum);
    kD <<<dim3(2560),   dim3(256), 0, stream>>>(out, accum);
}